// Round 1
// baseline (187.196 us; speedup 1.0000x reference)
//
#include <hip/hip_runtime.h>
#include <hip/hip_bf16.h>
#include <stdint.h>

// ---------------------------------------------------------------------------
// GroundingLoss: loss = mean_n [ (lse_a S[a,n] - S[n,n]) + (lse_b S[n,b] - S[n,n]) ]
// S[a,b] = (1/J) * sum_j ( sum_i softmax_i(sim[a,b,:,j]) * sim[a,b,i,j] )
// sim[a,b,i,j] = dot(x[a,i,:], z[b,j,:]),  N=256, I=J=32, K=256
//
// Strategy: bf16 MFMA (32x32x16) computes each 32x32 sim block per (a,b) pair
// fully in registers; softmax over i done in-register (C-layout: col=lane&31,
// rows = 16 regs x 2 lane-halves). Block = 4 waves = 8a x 4b pairs, wave =
// 2a x 4b. K tiled in 64-chunks staged to LDS with XOR swizzle (unit^token&7)
// so both ds_write_b128 and ds_read_b128 are bank-conflict-free.
// ---------------------------------------------------------------------------

typedef __attribute__((ext_vector_type(8))) short short8;    // 8 bf16 = 16B
typedef __attribute__((ext_vector_type(16))) float float16;  // 32x32 acc: 16 f32/lane

#define NTOK 256   // batch N (both a and b)
#define KDIM 256
#define BA 8       // a-rows per block
#define BB 4       // b-rows per block
#define KC 64      // k-chunk staged per LDS buffer

__device__ __forceinline__ unsigned short f2bf(float f) {
    unsigned int u = __float_as_uint(f);
    unsigned int r = (u + 0x7fffu + ((u >> 16) & 1u)) >> 16;  // RNE
    return (unsigned short)r;
}

// fp32 -> bf16 conversion of x and z into ws (straight [token][k] layout).
// 524288 units of 8 elems; x tokens 0..8191 then z tokens.
__global__ void conv_kernel(const float* __restrict__ x,
                            const float* __restrict__ z,
                            short8* __restrict__ outbf) {
    int uid = blockIdx.x * 256 + threadIdx.x;   // < 524288
    long e = (long)uid * 8;
    const float* src = (uid < 262144) ? (x + e) : (z + (e - 2097152));
    float4 f0 = ((const float4*)src)[0];
    float4 f1 = ((const float4*)src)[1];
    short8 v;
    v[0] = (short)f2bf(f0.x); v[1] = (short)f2bf(f0.y);
    v[2] = (short)f2bf(f0.z); v[3] = (short)f2bf(f0.w);
    v[4] = (short)f2bf(f1.x); v[5] = (short)f2bf(f1.y);
    v[6] = (short)f2bf(f1.z); v[7] = (short)f2bf(f1.w);
    outbf[uid] = v;
}

// Main fused kernel: computes S[a,b] for its 8x4 pair tile.
// grid = 32*64 = 2048 blocks, 256 threads.
template <bool F32SRC>
__global__ __launch_bounds__(256, 2)
void sim_kernel(const short8* __restrict__ xbf, const short8* __restrict__ zbf,
                const float* __restrict__ xf, const float* __restrict__ zf,
                float* __restrict__ S) {
    // tokens 0..255 = x rows (BA*32), 256..383 = z rows (BB*32); 8 units/token
    __shared__ short8 smem[(BA * 32 + BB * 32) * 8];   // 48 KB

    const int tid  = threadIdx.x;
    const int lane = tid & 63;
    const int wid  = tid >> 6;
    const int l31  = lane & 31;
    const int half = lane >> 5;
    const int l7   = lane & 7;

    const int bid = blockIdx.x;
    const int a0  = (bid >> 6) * BA;   // 0..248 step 8
    const int b0  = (bid & 63) * BB;   // 0..252 step 4

    // fragment token bases (smem unit index), token t -> units [t*8 .. t*8+7]
    const int tA0 = ((2 * wid + 0) * 32 + l31) * 8;
    const int tA1 = tA0 + 32 * 8;
    const int tB  = (256 + l31) * 8;   // + b*256

    float16 acc[2][4];
#pragma unroll
    for (int ai = 0; ai < 2; ai++)
#pragma unroll
        for (int b = 0; b < 4; b++)
#pragma unroll
            for (int r = 0; r < 16; r++) acc[ai][b][r] = 0.0f;

#pragma unroll
    for (int kc = 0; kc < KDIM / KC; kc++) {
        __syncthreads();
        // stage 3072 units (48KB): 12 per thread, consecutive tids ->
        // consecutive LDS units (conflict-free b128 writes). XOR swizzle is
        // applied on the *source* k-unit so LDS holds unit s = ku ^ (t&7).
#pragma unroll
        for (int it = 0; it < 12; it++) {
            const int u = tid + it * 256;       // 0..3071
            const int t = u >> 3;               // local token
            const int s = u & 7;                // LDS slot within row-chunk
            const int ku = s ^ (t & 7);         // source k-unit (swizzle)
            if (F32SRC) {
                const float* src = (t < 256)
                    ? (xf + ((long)(a0 * 32 + t) * KDIM + kc * KC + ku * 8))
                    : (zf + ((long)(b0 * 32 + (t - 256)) * KDIM + kc * KC + ku * 8));
                float4 f0 = ((const float4*)src)[0];
                float4 f1 = ((const float4*)src)[1];
                short8 v;
                v[0] = (short)f2bf(f0.x); v[1] = (short)f2bf(f0.y);
                v[2] = (short)f2bf(f0.z); v[3] = (short)f2bf(f0.w);
                v[4] = (short)f2bf(f1.x); v[5] = (short)f2bf(f1.y);
                v[6] = (short)f2bf(f1.z); v[7] = (short)f2bf(f1.w);
                smem[u] = v;
            } else {
                const short8* src = (t < 256)
                    ? (xbf + ((a0 * 32 + t) * 32 + kc * 8 + ku))
                    : (zbf + ((b0 * 32 + (t - 256)) * 32 + kc * 8 + ku));
                smem[u] = *src;
            }
        }
        __syncthreads();

        // 4 k-steps of 16 within this 64-chunk
#pragma unroll
        for (int ks = 0; ks < 4; ks++) {
            const int su = ((ks << 1) | half) ^ l7;   // swizzled unit
            short8 af0 = smem[tA0 + su];
            short8 af1 = smem[tA1 + su];
            short8 bf[4];
#pragma unroll
            for (int b = 0; b < 4; b++) bf[b] = smem[tB + b * 256 + su];
#pragma unroll
            for (int b = 0; b < 4; b++)
                acc[0][b] = __builtin_amdgcn_mfma_f32_32x32x16_bf16(af0, bf[b], acc[0][b], 0, 0, 0);
#pragma unroll
            for (int b = 0; b < 4; b++)
                acc[1][b] = __builtin_amdgcn_mfma_f32_32x32x16_bf16(af1, bf[b], acc[1][b], 0, 0, 0);
        }
    }

    // Epilogue: per pair, softmax over i (rows) for each column j = lane&31.
    // Column j's 32 values live in lanes j and j+32 (16 regs each).
#pragma unroll
    for (int ai = 0; ai < 2; ai++) {
#pragma unroll
        for (int b = 0; b < 4; b++) {
            float16 c = acc[ai][b];
            float m = c[0];
#pragma unroll
            for (int r = 1; r < 16; r++) m = fmaxf(m, c[r]);
            m = fmaxf(m, __shfl_xor(m, 32, 64));
            float se = 0.0f, swe = 0.0f;
#pragma unroll
            for (int r = 0; r < 16; r++) {
                float e = __expf(c[r] - m);
                se += e;
                swe = fmaf(e, c[r], swe);
            }
            se  += __shfl_xor(se, 32, 64);
            swe += __shfl_xor(swe, 32, 64);
            float cv = swe / se;   // weighted mean for column j
            // sum over j: both halves hold identical colvals -> 64-lane
            // butterfly gives 2*sum_j; S = sum_j/32 = butterfly/64.
#pragma unroll
            for (int off = 1; off < 64; off <<= 1) cv += __shfl_xor(cv, off, 64);
            if (lane == 0)
                S[(a0 + 2 * wid + ai) * NTOK + (b0 + b)] = cv * (1.0f / 64.0f);
        }
    }
}

// Loss epilogue over S [256x256]: one block, 256 threads (thread n owns n).
__global__ void loss_kernel(const float* __restrict__ S, float* __restrict__ out) {
    const int n = threadIdx.x;
    // column lse (over a) — coalesced
    float m = -1e30f;
    for (int a = 0; a < NTOK; a++) m = fmaxf(m, S[a * NTOK + n]);
    float s = 0.0f;
    for (int a = 0; a < NTOK; a++) s += __expf(S[a * NTOK + n] - m);
    float lse_col = m + __logf(s);
    // row lse (over b)
    float m2 = -1e30f;
    for (int b = 0; b < NTOK; b++) m2 = fmaxf(m2, S[n * NTOK + b]);
    float s2 = 0.0f;
    for (int b = 0; b < NTOK; b++) s2 += __expf(S[n * NTOK + b] - m2);
    float lse_row = m2 + __logf(s2);

    float diag = S[n * NTOK + n];
    float l = (lse_col - diag) + (lse_row - diag);

    // reduce sum over 256 threads
#pragma unroll
    for (int off = 1; off < 64; off <<= 1) l += __shfl_xor(l, off, 64);
    __shared__ float red[4];
    if ((n & 63) == 0) red[n >> 6] = l;
    __syncthreads();
    if (n == 0) out[0] = (red[0] + red[1] + red[2] + red[3]) * (1.0f / 256.0f);
}

extern "C" void kernel_launch(void* const* d_in, const int* in_sizes, int n_in,
                              void* d_out, int out_size, void* d_ws, size_t ws_size,
                              hipStream_t stream) {
    const float* x = (const float*)d_in[0];   // [256,32,256]
    const float* z = (const float*)d_in[1];   // [256,32,256]
    float* out = (float*)d_out;

    const size_t bf_bytes = 2ull * 2097152ull * 2ull;  // 8 MB (x+z in bf16)
    const size_t s_bytes  = 256ull * 256ull * 4ull;    // 256 KB

    if (ws_size >= bf_bytes + s_bytes) {
        short8* xbf = (short8*)d_ws;                 // 262144 units
        short8* zbf = xbf + 262144;
        float*  S   = (float*)((char*)d_ws + bf_bytes);
        conv_kernel<<<2048, 256, 0, stream>>>(x, z, (short8*)d_ws);
        sim_kernel<false><<<2048, 256, 0, stream>>>(xbf, zbf, x, z, S);
        loss_kernel<<<1, 256, 0, stream>>>(S, out);
    } else {
        float* S = (float*)d_ws;   // 256 KB
        sim_kernel<true><<<2048, 256, 0, stream>>>(nullptr, nullptr, x, z, S);
        loss_kernel<<<1, 256, 0, stream>>>(S, out);
    }
}

// Round 2
// 120.599 us; speedup vs baseline: 1.5522x; 1.5522x over previous
//
#include <hip/hip_runtime.h>
#include <hip/hip_bf16.h>
#include <stdint.h>

// ---------------------------------------------------------------------------
// GroundingLoss: loss = mean_n [ (lse_a S[a,n] - S[n,n]) + (lse_b S[n,b] - S[n,n]) ]
// S[a,b] = (1/J) * sum_j ( sum_i softmax_i(sim[a,b,:,j]) * sim[a,b,i,j] )
// sim[a,b,i,j] = dot(x[a,i,:], z[b,j,:]),  N=256, I=J=32, K=256
//
// R1: loss stage parallelized (was 1 block / 75us, latency-bound at 1 CU).
// Now: loss_part (64 blocks, 1 wave per n, shuffle-only reductions) writes
// per-n losses to ws; loss_reduce (1 block, 64 threads) averages them.
// ---------------------------------------------------------------------------

typedef __attribute__((ext_vector_type(8))) short short8;    // 8 bf16 = 16B
typedef __attribute__((ext_vector_type(16))) float float16;  // 32x32 acc: 16 f32/lane

#define NTOK 256   // batch N (both a and b)
#define KDIM 256
#define BA 8       // a-rows per block
#define BB 4       // b-rows per block
#define KC 64      // k-chunk staged per LDS buffer

__device__ __forceinline__ unsigned short f2bf(float f) {
    unsigned int u = __float_as_uint(f);
    unsigned int r = (u + 0x7fffu + ((u >> 16) & 1u)) >> 16;  // RNE
    return (unsigned short)r;
}

// fp32 -> bf16 conversion of x and z into ws (straight [token][k] layout).
// 524288 units of 8 elems; x tokens 0..8191 then z tokens.
__global__ void conv_kernel(const float* __restrict__ x,
                            const float* __restrict__ z,
                            short8* __restrict__ outbf) {
    int uid = blockIdx.x * 256 + threadIdx.x;   // < 524288
    long e = (long)uid * 8;
    const float* src = (uid < 262144) ? (x + e) : (z + (e - 2097152));
    float4 f0 = ((const float4*)src)[0];
    float4 f1 = ((const float4*)src)[1];
    short8 v;
    v[0] = (short)f2bf(f0.x); v[1] = (short)f2bf(f0.y);
    v[2] = (short)f2bf(f0.z); v[3] = (short)f2bf(f0.w);
    v[4] = (short)f2bf(f1.x); v[5] = (short)f2bf(f1.y);
    v[6] = (short)f2bf(f1.z); v[7] = (short)f2bf(f1.w);
    outbf[uid] = v;
}

// Main fused kernel: computes S[a,b] for its 8x4 pair tile.
// grid = 32*64 = 2048 blocks, 256 threads.
template <bool F32SRC>
__global__ __launch_bounds__(256, 2)
void sim_kernel(const short8* __restrict__ xbf, const short8* __restrict__ zbf,
                const float* __restrict__ xf, const float* __restrict__ zf,
                float* __restrict__ S) {
    // tokens 0..255 = x rows (BA*32), 256..383 = z rows (BB*32); 8 units/token
    __shared__ short8 smem[(BA * 32 + BB * 32) * 8];   // 48 KB

    const int tid  = threadIdx.x;
    const int lane = tid & 63;
    const int wid  = tid >> 6;
    const int l31  = lane & 31;
    const int half = lane >> 5;
    const int l7   = lane & 7;

    const int bid = blockIdx.x;
    const int a0  = (bid >> 6) * BA;   // 0..248 step 8
    const int b0  = (bid & 63) * BB;   // 0..252 step 4

    // fragment token bases (smem unit index), token t -> units [t*8 .. t*8+7]
    const int tA0 = ((2 * wid + 0) * 32 + l31) * 8;
    const int tA1 = tA0 + 32 * 8;
    const int tB  = (256 + l31) * 8;   // + b*256

    float16 acc[2][4];
#pragma unroll
    for (int ai = 0; ai < 2; ai++)
#pragma unroll
        for (int b = 0; b < 4; b++)
#pragma unroll
            for (int r = 0; r < 16; r++) acc[ai][b][r] = 0.0f;

#pragma unroll
    for (int kc = 0; kc < KDIM / KC; kc++) {
        __syncthreads();
        // stage 3072 units (48KB): 12 per thread, consecutive tids ->
        // consecutive LDS units (conflict-free b128 writes). XOR swizzle is
        // applied on the *source* k-unit so LDS holds unit s = ku ^ (t&7).
#pragma unroll
        for (int it = 0; it < 12; it++) {
            const int u = tid + it * 256;       // 0..3071
            const int t = u >> 3;               // local token
            const int s = u & 7;                // LDS slot within row-chunk
            const int ku = s ^ (t & 7);         // source k-unit (swizzle)
            if (F32SRC) {
                const float* src = (t < 256)
                    ? (xf + ((long)(a0 * 32 + t) * KDIM + kc * KC + ku * 8))
                    : (zf + ((long)(b0 * 32 + (t - 256)) * KDIM + kc * KC + ku * 8));
                float4 f0 = ((const float4*)src)[0];
                float4 f1 = ((const float4*)src)[1];
                short8 v;
                v[0] = (short)f2bf(f0.x); v[1] = (short)f2bf(f0.y);
                v[2] = (short)f2bf(f0.z); v[3] = (short)f2bf(f0.w);
                v[4] = (short)f2bf(f1.x); v[5] = (short)f2bf(f1.y);
                v[6] = (short)f2bf(f1.z); v[7] = (short)f2bf(f1.w);
                smem[u] = v;
            } else {
                const short8* src = (t < 256)
                    ? (xbf + ((a0 * 32 + t) * 32 + kc * 8 + ku))
                    : (zbf + ((b0 * 32 + (t - 256)) * 32 + kc * 8 + ku));
                smem[u] = *src;
            }
        }
        __syncthreads();

        // 4 k-steps of 16 within this 64-chunk
#pragma unroll
        for (int ks = 0; ks < 4; ks++) {
            const int su = ((ks << 1) | half) ^ l7;   // swizzled unit
            short8 af0 = smem[tA0 + su];
            short8 af1 = smem[tA1 + su];
            short8 bf[4];
#pragma unroll
            for (int b = 0; b < 4; b++) bf[b] = smem[tB + b * 256 + su];
#pragma unroll
            for (int b = 0; b < 4; b++)
                acc[0][b] = __builtin_amdgcn_mfma_f32_32x32x16_bf16(af0, bf[b], acc[0][b], 0, 0, 0);
#pragma unroll
            for (int b = 0; b < 4; b++)
                acc[1][b] = __builtin_amdgcn_mfma_f32_32x32x16_bf16(af1, bf[b], acc[1][b], 0, 0, 0);
        }
    }

    // Epilogue: per pair, softmax over i (rows) for each column j = lane&31.
    // Column j's 32 values live in lanes j and j+32 (16 regs each).
#pragma unroll
    for (int ai = 0; ai < 2; ai++) {
#pragma unroll
        for (int b = 0; b < 4; b++) {
            float16 c = acc[ai][b];
            float m = c[0];
#pragma unroll
            for (int r = 1; r < 16; r++) m = fmaxf(m, c[r]);
            m = fmaxf(m, __shfl_xor(m, 32, 64));
            float se = 0.0f, swe = 0.0f;
#pragma unroll
            for (int r = 0; r < 16; r++) {
                float e = __expf(c[r] - m);
                se += e;
                swe = fmaf(e, c[r], swe);
            }
            se  += __shfl_xor(se, 32, 64);
            swe += __shfl_xor(swe, 32, 64);
            float cv = swe / se;   // weighted mean for column j
            // sum over j: both halves hold identical colvals -> 64-lane
            // butterfly gives 2*sum_j; S = sum_j/32 = butterfly/64.
#pragma unroll
            for (int off = 1; off < 64; off <<= 1) cv += __shfl_xor(cv, off, 64);
            if (lane == 0)
                S[(a0 + 2 * wid + ai) * NTOK + (b0 + b)] = cv * (1.0f / 64.0f);
        }
    }
}

// Per-n loss: 64 blocks x 256 threads; wave w of block handles n = bid*4+w.
// Each lane holds 4 column elems + 4 row elems; shuffle-only reductions.
__global__ void loss_part(const float* __restrict__ S, float* __restrict__ lossn) {
    const int lane = threadIdx.x & 63;
    const int wid  = threadIdx.x >> 6;
    const int n    = blockIdx.x * 4 + wid;

    float cv[4], rv[4];
#pragma unroll
    for (int k = 0; k < 4; k++) {
        const int t = lane + 64 * k;
        cv[k] = S[t * NTOK + n];   // column: over a
        rv[k] = S[n * NTOK + t];   // row: over b
    }
    // lse over column
    float m = fmaxf(fmaxf(cv[0], cv[1]), fmaxf(cv[2], cv[3]));
#pragma unroll
    for (int off = 1; off < 64; off <<= 1) m = fmaxf(m, __shfl_xor(m, off, 64));
    float s = 0.0f;
#pragma unroll
    for (int k = 0; k < 4; k++) s += __expf(cv[k] - m);
#pragma unroll
    for (int off = 1; off < 64; off <<= 1) s += __shfl_xor(s, off, 64);
    float lse_col = m + __logf(s);

    // lse over row
    float m2 = fmaxf(fmaxf(rv[0], rv[1]), fmaxf(rv[2], rv[3]));
#pragma unroll
    for (int off = 1; off < 64; off <<= 1) m2 = fmaxf(m2, __shfl_xor(m2, off, 64));
    float s2 = 0.0f;
#pragma unroll
    for (int k = 0; k < 4; k++) s2 += __expf(rv[k] - m2);
#pragma unroll
    for (int off = 1; off < 64; off <<= 1) s2 += __shfl_xor(s2, off, 64);
    float lse_row = m2 + __logf(s2);

    if (lane == 0) {
        float diag = S[n * NTOK + n];
        lossn[n] = (lse_col - diag) + (lse_row - diag);
    }
}

// Final mean over 256 per-n losses: 1 block, 64 threads.
__global__ void loss_reduce(const float* __restrict__ lossn, float* __restrict__ out) {
    const int lane = threadIdx.x;
    float s = 0.0f;
#pragma unroll
    for (int k = 0; k < 4; k++) s += lossn[lane + 64 * k];
#pragma unroll
    for (int off = 1; off < 64; off <<= 1) s += __shfl_xor(s, off, 64);
    if (lane == 0) out[0] = s * (1.0f / 256.0f);
}

extern "C" void kernel_launch(void* const* d_in, const int* in_sizes, int n_in,
                              void* d_out, int out_size, void* d_ws, size_t ws_size,
                              hipStream_t stream) {
    const float* x = (const float*)d_in[0];   // [256,32,256]
    const float* z = (const float*)d_in[1];   // [256,32,256]
    float* out = (float*)d_out;

    const size_t bf_bytes = 2ull * 2097152ull * 2ull;  // 8 MB (x+z in bf16)
    const size_t s_bytes  = 256ull * 256ull * 4ull;    // 256 KB
    const size_t l_bytes  = 256ull * 4ull;             // per-n losses

    if (ws_size >= bf_bytes + s_bytes + l_bytes) {
        short8* xbf = (short8*)d_ws;                 // 262144 units
        short8* zbf = xbf + 262144;
        float*  S   = (float*)((char*)d_ws + bf_bytes);
        float*  ln  = (float*)((char*)d_ws + bf_bytes + s_bytes);
        conv_kernel<<<2048, 256, 0, stream>>>(x, z, (short8*)d_ws);
        sim_kernel<false><<<2048, 256, 0, stream>>>(xbf, zbf, x, z, S);
        loss_part<<<64, 256, 0, stream>>>(S, ln);
        loss_reduce<<<1, 64, 0, stream>>>(ln, out);
    } else {
        float* S  = (float*)d_ws;   // 256 KB
        float* ln = (float*)((char*)d_ws + s_bytes);
        sim_kernel<true><<<2048, 256, 0, stream>>>(nullptr, nullptr, x, z, S);
        loss_part<<<64, 256, 0, stream>>>(S, ln);
        loss_reduce<<<1, 64, 0, stream>>>(ln, out);
    }
}

// Round 3
// 119.407 us; speedup vs baseline: 1.5677x; 1.0100x over previous
//
#include <hip/hip_runtime.h>
#include <hip/hip_bf16.h>
#include <stdint.h>

// ---------------------------------------------------------------------------
// GroundingLoss fused pipeline, R3:
//   conv_kernel : fp32 -> bf16 in FRAGMENT-MAJOR layout
//                 unit(g, ks, half, l31) = g*1024 + ks*64 + half*32 + l31
//                 (g = token group of 32 rows = one a/b index; 16B units)
//                 Every MFMA fragment is then a fully-coalesced 1KB
//                 global_load_dwordx4 (base + lane*16B). No LDS at all.
//   sim_kernel  : 2048 blocks x 4 waves; wave = 2a x 4b 32x32 tiles,
//                 K=256 via 16 x mfma_f32_32x32x16_bf16; softmax-weighted
//                 reduction in-register (C-layout col=lane&31).
//   loss_part   : 64 blocks, wave per n, shuffle lse; one atomicAdd per
//                 block into d_out (zeroed by conv_kernel).
// ---------------------------------------------------------------------------

typedef __attribute__((ext_vector_type(8))) short short8;    // 8 bf16 = 16B
typedef __attribute__((ext_vector_type(16))) float float16;  // 32x32 acc

#define NTOK 256
#define KDIM 256

__device__ __forceinline__ unsigned short f2bf(float f) {
    unsigned int u = __float_as_uint(f);
    unsigned int r = (u + 0x7fffu + ((u >> 16) & 1u)) >> 16;  // RNE
    return (unsigned short)r;
}

__device__ __forceinline__ short8 cvt8(const float* p) {
    float4 f0 = ((const float4*)p)[0];
    float4 f1 = ((const float4*)p)[1];
    short8 v;
    v[0] = (short)f2bf(f0.x); v[1] = (short)f2bf(f0.y);
    v[2] = (short)f2bf(f0.z); v[3] = (short)f2bf(f0.w);
    v[4] = (short)f2bf(f1.x); v[5] = (short)f2bf(f1.y);
    v[6] = (short)f2bf(f1.z); v[7] = (short)f2bf(f1.w);
    return v;
}

// One thread per output unit. x units 0..262143, z units 262144..524287.
// Writes coalesced; reads are 32B chunks, line-complete within each wave.
__global__ void conv_kernel(const float* __restrict__ x,
                            const float* __restrict__ z,
                            short8* __restrict__ outbf,
                            float* __restrict__ out0) {
    const int uid = blockIdx.x * 256 + threadIdx.x;
    if (uid == 0) out0[0] = 0.0f;   // accumulator for atomic loss
    const int u = uid & 262143;
    const float* src = (uid < 262144) ? x : z;
    const int g  = u >> 10;
    const int r  = u & 1023;
    const int ks = r >> 6;
    const int h  = (r >> 5) & 1;
    const int l  = r & 31;
    outbf[uid] = cvt8(src + ((g * 32 + l) * KDIM + ks * 16 + h * 8));
}

// grid = 2048 (32 a-groups x 64 b-groups), 256 threads.
// F32SRC: correctness fallback reading fp32 directly (no ws conversion).
template <bool F32SRC>
__global__ __launch_bounds__(256, 2)
void sim_kernel(const short8* __restrict__ xbf, const short8* __restrict__ zbf,
                const float* __restrict__ xf, const float* __restrict__ zf,
                float* __restrict__ S) {
    const int tid  = threadIdx.x;
    const int lane = tid & 63;
    const int wid  = tid >> 6;
    const int l31  = lane & 31;
    const int half = lane >> 5;
    const int bid  = blockIdx.x;
    const int a0   = (bid >> 6) * 8;
    const int b0   = (bid & 63) * 4;

    // fragment-major pointers: frag(g, ks) at g*1024 + ks*64 + lane
    const short8* pa0 = xbf + (a0 + 2 * wid) * 1024 + lane;
    const short8* pa1 = pa0 + 1024;
    const short8* pb  = zbf + b0 * 1024 + lane;

    // f32 fallback pointers: row-major source
    const float* fa0 = xf + (((a0 + 2 * wid) * 32 + l31) * KDIM + half * 8);
    const float* fa1 = fa0 + 32 * KDIM;
    const float* fb  = zf + ((b0 * 32 + l31) * KDIM + half * 8);

    float16 acc[2][4];
#pragma unroll
    for (int ai = 0; ai < 2; ai++)
#pragma unroll
        for (int b = 0; b < 4; b++)
#pragma unroll
            for (int r = 0; r < 16; r++) acc[ai][b][r] = 0.0f;

    for (int kk = 0; kk < 4; kk++) {
#pragma unroll
        for (int ki = 0; ki < 4; ki++) {
            short8 af0, af1, bfr[4];
            if (F32SRC) {
                const int ks = kk * 4 + ki;
                af0 = cvt8(fa0 + ks * 16);
                af1 = cvt8(fa1 + ks * 16);
#pragma unroll
                for (int b = 0; b < 4; b++)
                    bfr[b] = cvt8(fb + b * 32 * KDIM + ks * 16);
            } else {
                const int off = ki * 64;
                af0 = pa0[off];
                af1 = pa1[off];
#pragma unroll
                for (int b = 0; b < 4; b++) bfr[b] = pb[b * 1024 + off];
            }
#pragma unroll
            for (int b = 0; b < 4; b++)
                acc[0][b] = __builtin_amdgcn_mfma_f32_32x32x16_bf16(af0, bfr[b], acc[0][b], 0, 0, 0);
#pragma unroll
            for (int b = 0; b < 4; b++)
                acc[1][b] = __builtin_amdgcn_mfma_f32_32x32x16_bf16(af1, bfr[b], acc[1][b], 0, 0, 0);
        }
        if (!F32SRC) { pa0 += 256; pa1 += 256; pb += 256; }
    }

    // Epilogue: softmax over i (rows) per column j = lane&31, then mean over j.
#pragma unroll
    for (int ai = 0; ai < 2; ai++) {
#pragma unroll
        for (int b = 0; b < 4; b++) {
            float16 c = acc[ai][b];
            float m = c[0];
#pragma unroll
            for (int r = 1; r < 16; r++) m = fmaxf(m, c[r]);
            m = fmaxf(m, __shfl_xor(m, 32, 64));
            float se = 0.0f, swe = 0.0f;
#pragma unroll
            for (int r = 0; r < 16; r++) {
                float e = __expf(c[r] - m);
                se += e;
                swe = fmaf(e, c[r], swe);
            }
            se  += __shfl_xor(se, 32, 64);
            swe += __shfl_xor(swe, 32, 64);
            float cv = swe / se;
#pragma unroll
            for (int off = 1; off < 64; off <<= 1) cv += __shfl_xor(cv, off, 64);
            if (lane == 0)
                S[(a0 + 2 * wid + ai) * NTOK + (b0 + b)] = cv * (1.0f / 64.0f);
        }
    }
}

// 64 blocks x 256 threads; wave w handles n = bid*4 + w. One atomicAdd/block.
__global__ void loss_part(const float* __restrict__ S, float* __restrict__ out) {
    const int lane = threadIdx.x & 63;
    const int wid  = threadIdx.x >> 6;
    const int n    = blockIdx.x * 4 + wid;

    float cv[4], rv[4];
#pragma unroll
    for (int k = 0; k < 4; k++) {
        const int t = lane + 64 * k;
        cv[k] = S[t * NTOK + n];
        rv[k] = S[n * NTOK + t];
    }
    float m = fmaxf(fmaxf(cv[0], cv[1]), fmaxf(cv[2], cv[3]));
#pragma unroll
    for (int off = 1; off < 64; off <<= 1) m = fmaxf(m, __shfl_xor(m, off, 64));
    float s = 0.0f;
#pragma unroll
    for (int k = 0; k < 4; k++) s += __expf(cv[k] - m);
#pragma unroll
    for (int off = 1; off < 64; off <<= 1) s += __shfl_xor(s, off, 64);
    float lse_col = m + __logf(s);

    float m2 = fmaxf(fmaxf(rv[0], rv[1]), fmaxf(rv[2], rv[3]));
#pragma unroll
    for (int off = 1; off < 64; off <<= 1) m2 = fmaxf(m2, __shfl_xor(m2, off, 64));
    float s2 = 0.0f;
#pragma unroll
    for (int k = 0; k < 4; k++) s2 += __expf(rv[k] - m2);
#pragma unroll
    for (int off = 1; off < 64; off <<= 1) s2 += __shfl_xor(s2, off, 64);
    float lse_row = m2 + __logf(s2);

    __shared__ float red[4];
    if (lane == 0) {
        float diag = S[n * NTOK + n];
        red[wid] = (lse_col - diag) + (lse_row - diag);
    }
    __syncthreads();
    if (threadIdx.x == 0)
        atomicAdd(out, (red[0] + red[1] + red[2] + red[3]) * (1.0f / 256.0f));
}

__global__ void zero_kernel(float* __restrict__ out) {
    out[0] = 0.0f;
}

extern "C" void kernel_launch(void* const* d_in, const int* in_sizes, int n_in,
                              void* d_out, int out_size, void* d_ws, size_t ws_size,
                              hipStream_t stream) {
    const float* x = (const float*)d_in[0];   // [256,32,256]
    const float* z = (const float*)d_in[1];   // [256,32,256]
    float* out = (float*)d_out;

    const size_t bf_bytes = 524288ull * 16ull;         // 8 MB fragment-major
    const size_t s_bytes  = 256ull * 256ull * 4ull;    // 256 KB

    if (ws_size >= bf_bytes + s_bytes) {
        short8* xbf = (short8*)d_ws;          // 262144 units
        short8* zbf = xbf + 262144;
        float*  S   = (float*)((char*)d_ws + bf_bytes);
        conv_kernel<<<2048, 256, 0, stream>>>(x, z, (short8*)d_ws, out);
        sim_kernel<false><<<2048, 256, 0, stream>>>(xbf, zbf, nullptr, nullptr, S);
        loss_part<<<64, 256, 0, stream>>>(S, out);
    } else {
        float* S = (float*)d_ws;              // 256 KB
        zero_kernel<<<1, 1, 0, stream>>>(out);
        sim_kernel<true><<<2048, 256, 0, stream>>>(nullptr, nullptr, x, z, S);
        loss_part<<<64, 256, 0, stream>>>(S, out);
    }
}

// Round 4
// 117.948 us; speedup vs baseline: 1.5871x; 1.0124x over previous
//
#include <hip/hip_runtime.h>
#include <hip/hip_bf16.h>
#include <stdint.h>

// ---------------------------------------------------------------------------
// GroundingLoss fused pipeline, R4.
// R3 -> R4: sim_kernel retiled for OCCUPANCY. R2/R3 both sat at 56us with
// MfmaUtil 24.5% regardless of LDS use -> latency-bound at 2 waves/SIMD
// (128 AGPR acc + 108 VGPR). Now wave = 2a x 2b tiles (64 AGPR acc),
// block = 4a x 4b groups, grid 4096, __launch_bounds__(256,4) -> 4 waves/SIMD.
// Fragment-major bf16 layout in ws (from conv_kernel) keeps every MFMA
// fragment a fully-coalesced 1KB global_load_dwordx4; no LDS anywhere.
// ---------------------------------------------------------------------------

typedef __attribute__((ext_vector_type(8))) short short8;    // 8 bf16 = 16B
typedef __attribute__((ext_vector_type(16))) float float16;  // 32x32 acc

#define NTOK 256
#define KDIM 256

__device__ __forceinline__ unsigned short f2bf(float f) {
    unsigned int u = __float_as_uint(f);
    unsigned int r = (u + 0x7fffu + ((u >> 16) & 1u)) >> 16;  // RNE
    return (unsigned short)r;
}

__device__ __forceinline__ short8 cvt8(const float* p) {
    float4 f0 = ((const float4*)p)[0];
    float4 f1 = ((const float4*)p)[1];
    short8 v;
    v[0] = (short)f2bf(f0.x); v[1] = (short)f2bf(f0.y);
    v[2] = (short)f2bf(f0.z); v[3] = (short)f2bf(f0.w);
    v[4] = (short)f2bf(f1.x); v[5] = (short)f2bf(f1.y);
    v[6] = (short)f2bf(f1.z); v[7] = (short)f2bf(f1.w);
    return v;
}

// fp32 -> bf16 fragment-major: unit(g, ks, half, l31) = g*1024 + ks*64 + half*32 + l31.
// One thread per 16B output unit; writes coalesced, reads 32B strided (2x fetch amp).
__global__ void conv_kernel(const float* __restrict__ x,
                            const float* __restrict__ z,
                            short8* __restrict__ outbf,
                            float* __restrict__ out0) {
    const int uid = blockIdx.x * 256 + threadIdx.x;
    if (uid == 0) out0[0] = 0.0f;   // loss accumulator (loss_part atomicAdds)
    const int u = uid & 262143;
    const float* src = (uid < 262144) ? x : z;
    const int g  = u >> 10;
    const int r  = u & 1023;
    const int ks = r >> 6;
    const int h  = (r >> 5) & 1;
    const int l  = r & 31;
    outbf[uid] = cvt8(src + ((g * 32 + l) * KDIM + ks * 16 + h * 8));
}

// grid = 4096 (64 a-groups x 64 b-groups of 4), 256 threads, 4 waves/SIMD.
template <bool F32SRC>
__global__ __launch_bounds__(256, 4)
void sim_kernel(const short8* __restrict__ xbf, const short8* __restrict__ zbf,
                const float* __restrict__ xf, const float* __restrict__ zf,
                float* __restrict__ S) {
    const int tid  = threadIdx.x;
    const int lane = tid & 63;
    const int wid  = tid >> 6;
    const int aw   = wid >> 1;      // 0..1
    const int bw   = wid & 1;       // 0..1
    const int l31  = lane & 31;
    const int half = lane >> 5;
    const int bid  = blockIdx.x;
    const int a0   = (bid >> 6) * 4;
    const int b0   = (bid & 63) * 4;

    const int ag = a0 + 2 * aw;     // first a-group of this wave
    const int bg = b0 + 2 * bw;     // first b-group of this wave

    // fragment-major pointers: frag(g, ks) at g*1024 + ks*64 + lane
    const short8* pa = xbf + ag * 1024 + lane;
    const short8* pb = zbf + bg * 1024 + lane;

    // f32 fallback (row-major source, in-flight convert)
    const float* fa = xf + ((ag * 32 + l31) * KDIM + half * 8);
    const float* fb = zf + ((bg * 32 + l31) * KDIM + half * 8);

    float16 acc[2][2];
#pragma unroll
    for (int ai = 0; ai < 2; ai++)
#pragma unroll
        for (int bi = 0; bi < 2; bi++)
#pragma unroll
            for (int r = 0; r < 16; r++) acc[ai][bi][r] = 0.0f;

#pragma unroll 4
    for (int ks = 0; ks < 16; ks++) {
        short8 a0f, a1f, b0f, b1f;
        if (F32SRC) {
            a0f = cvt8(fa + ks * 16);
            a1f = cvt8(fa + 32 * KDIM + ks * 16);
            b0f = cvt8(fb + ks * 16);
            b1f = cvt8(fb + 32 * KDIM + ks * 16);
        } else {
            const int off = ks * 64;
            a0f = pa[off];
            a1f = pa[off + 1024];
            b0f = pb[off];
            b1f = pb[off + 1024];
        }
        acc[0][0] = __builtin_amdgcn_mfma_f32_32x32x16_bf16(a0f, b0f, acc[0][0], 0, 0, 0);
        acc[0][1] = __builtin_amdgcn_mfma_f32_32x32x16_bf16(a0f, b1f, acc[0][1], 0, 0, 0);
        acc[1][0] = __builtin_amdgcn_mfma_f32_32x32x16_bf16(a1f, b0f, acc[1][0], 0, 0, 0);
        acc[1][1] = __builtin_amdgcn_mfma_f32_32x32x16_bf16(a1f, b1f, acc[1][1], 0, 0, 0);
    }

    // Epilogue: softmax over i (rows) per column j = lane&31, then mean over j.
#pragma unroll
    for (int ai = 0; ai < 2; ai++) {
#pragma unroll
        for (int bi = 0; bi < 2; bi++) {
            float16 c = acc[ai][bi];
            float m = c[0];
#pragma unroll
            for (int r = 1; r < 16; r++) m = fmaxf(m, c[r]);
            m = fmaxf(m, __shfl_xor(m, 32, 64));
            float se = 0.0f, swe = 0.0f;
#pragma unroll
            for (int r = 0; r < 16; r++) {
                float e = __expf(c[r] - m);
                se += e;
                swe = fmaf(e, c[r], swe);
            }
            se  += __shfl_xor(se, 32, 64);
            swe += __shfl_xor(swe, 32, 64);
            float cv = swe / se;   // column-j weighted mean (identical in both halves)
            // all-reduce over the 32 columns (5-step butterfly within half)
#pragma unroll
            for (int off = 1; off < 32; off <<= 1) cv += __shfl_xor(cv, off, 64);
            if (lane == 0)
                S[(ag + ai) * NTOK + (bg + bi)] = cv * (1.0f / 32.0f);
        }
    }
}

// 64 blocks x 256 threads; wave w handles n = bid*4 + w. One atomicAdd/block.
__global__ void loss_part(const float* __restrict__ S, float* __restrict__ out) {
    const int lane = threadIdx.x & 63;
    const int wid  = threadIdx.x >> 6;
    const int n    = blockIdx.x * 4 + wid;

    float cv[4], rv[4];
#pragma unroll
    for (int k = 0; k < 4; k++) {
        const int t = lane + 64 * k;
        cv[k] = S[t * NTOK + n];
        rv[k] = S[n * NTOK + t];
    }
    float m = fmaxf(fmaxf(cv[0], cv[1]), fmaxf(cv[2], cv[3]));
#pragma unroll
    for (int off = 1; off < 64; off <<= 1) m = fmaxf(m, __shfl_xor(m, off, 64));
    float s = 0.0f;
#pragma unroll
    for (int k = 0; k < 4; k++) s += __expf(cv[k] - m);
#pragma unroll
    for (int off = 1; off < 64; off <<= 1) s += __shfl_xor(s, off, 64);
    float lse_col = m + __logf(s);

    float m2 = fmaxf(fmaxf(rv[0], rv[1]), fmaxf(rv[2], rv[3]));
#pragma unroll
    for (int off = 1; off < 64; off <<= 1) m2 = fmaxf(m2, __shfl_xor(m2, off, 64));
    float s2 = 0.0f;
#pragma unroll
    for (int k = 0; k < 4; k++) s2 += __expf(rv[k] - m2);
#pragma unroll
    for (int off = 1; off < 64; off <<= 1) s2 += __shfl_xor(s2, off, 64);
    float lse_row = m2 + __logf(s2);

    __shared__ float red[4];
    if (lane == 0) {
        float diag = S[n * NTOK + n];
        red[wid] = (lse_col - diag) + (lse_row - diag);
    }
    __syncthreads();
    if (threadIdx.x == 0)
        atomicAdd(out, (red[0] + red[1] + red[2] + red[3]) * (1.0f / 256.0f));
}

__global__ void zero_kernel(float* __restrict__ out) {
    out[0] = 0.0f;
}

extern "C" void kernel_launch(void* const* d_in, const int* in_sizes, int n_in,
                              void* d_out, int out_size, void* d_ws, size_t ws_size,
                              hipStream_t stream) {
    const float* x = (const float*)d_in[0];   // [256,32,256]
    const float* z = (const float*)d_in[1];   // [256,32,256]
    float* out = (float*)d_out;

    const size_t bf_bytes = 524288ull * 16ull;         // 8 MB fragment-major
    const size_t s_bytes  = 256ull * 256ull * 4ull;    // 256 KB

    if (ws_size >= bf_bytes + s_bytes) {
        short8* xbf = (short8*)d_ws;          // 262144 units
        short8* zbf = xbf + 262144;
        float*  S   = (float*)((char*)d_ws + bf_bytes);
        conv_kernel<<<2048, 256, 0, stream>>>(x, z, (short8*)d_ws, out);
        sim_kernel<false><<<4096, 256, 0, stream>>>(xbf, zbf, nullptr, nullptr, S);
        loss_part<<<64, 256, 0, stream>>>(S, out);
    } else {
        float* S = (float*)d_ws;              // 256 KB
        zero_kernel<<<1, 1, 0, stream>>>(out);
        sim_kernel<true><<<4096, 256, 0, stream>>>(nullptr, nullptr, x, z, S);
        loss_part<<<64, 256, 0, stream>>>(S, out);
    }
}